// Round 1
// baseline (314.363 us; speedup 1.0000x reference)
//
#include <hip/hip_runtime.h>
#include <hip/hip_bf16.h>
#include <type_traits>

// Problem constants: N=4, Sq=2048, Skv=4096, E=1024, H=16, D=64, C=512
// Float tensors are FP32 in global; mask int32; output fp32.
#define NB   4
#define SQ   2048
#define SKV  4096
#define EMB  1024
#define CDIM 512
#define PPB  8        // positions per attention block (double-buffered pipeline)

typedef __attribute__((ext_vector_type(8))) short short8;
typedef __attribute__((ext_vector_type(4))) float f32x4;

__device__ __forceinline__ float b2f(ushort u) {
    union { unsigned int i; float f; } v;
    v.i = ((unsigned int)u) << 16;
    return v.f;
}
__device__ __forceinline__ ushort f2b(float f) {
    union { float f; unsigned int i; } v; v.f = f;
    unsigned int x = v.i;
    return (ushort)((x + 0x7fffu + ((x >> 16) & 1u)) >> 16);   // RNE
}

// async global->LDS, 16B per lane; LDS dest = wave-uniform base + lane*16
__device__ __forceinline__ void glds16(const ushort* gp, ushort* lp) {
    __builtin_amdgcn_global_load_lds(
        (const __attribute__((address_space(1))) unsigned int*)gp,
        (__attribute__((address_space(3))) unsigned int*)lp,
        16, 0, 0);
}

// ---------------------------------------------------------------------------
// f32 -> bf16 bulk convert (memory-bound, float4/ushort4)
// ---------------------------------------------------------------------------
__global__ __launch_bounds__(256)
void cvt_f32_bf16(const float* __restrict__ in, ushort* __restrict__ out, int n4)
{
    const int i = blockIdx.x * 256 + threadIdx.x;
    if (i < n4) {
        float4 v = ((const float4*)in)[i];
        ushort4 o;
        o.x = f2b(v.x); o.y = f2b(v.y); o.z = f2b(v.z); o.w = f2b(v.w);
        ((ushort4*)out)[i] = o;
    }
}

// ---------------------------------------------------------------------------
// Pure-bf16 GEMM (m97 structure): C[m,n] = sum_k A[m,k]*B[n,k] + bias[n]
// (unchanged this round)
// ---------------------------------------------------------------------------
template <typename OT>
__global__ __launch_bounds__(256)
void gemm_bt_bias(const ushort* __restrict__ A, const ushort* __restrict__ B,
                  const float* __restrict__ bias, OT* __restrict__ C,
                  int M, int Nn, int K)
{
    __shared__ __attribute__((aligned(16))) ushort As[128 * 32];
    __shared__ __attribute__((aligned(16))) ushort Bs[128 * 32];

    const int tid  = threadIdx.x;
    const int wave = tid >> 6;
    const int lane = tid & 63;
    const int quad = lane >> 4;
    const int l16  = lane & 15;
    const int wr   = wave >> 1;   // wave row (64 rows of M)
    const int wc   = wave & 1;    // wave col (64 cols of N)

    const long mBase = (long)blockIdx.x * 128;
    const long nBase = (long)blockIdx.y * 128;

    const ushort* Ablk = A + mBase * K;
    const ushort* Bblk = B + nBase * K;

    const int lr = lane >> 2;
    const int lc = (lane & 3) * 8;
    const int c0 = wave * 2, c1 = wave * 2 + 1;
    const ushort* aG0 = Ablk + (long)(c0 * 16 + lr) * K + lc;
    const ushort* aG1 = Ablk + (long)(c1 * 16 + lr) * K + lc;
    const ushort* bG0 = Bblk + (long)(c0 * 16 + lr) * K + lc;
    const ushort* bG1 = Bblk + (long)(c1 * 16 + lr) * K + lc;
    ushort* aL0 = As + c0 * 512;
    ushort* aL1 = As + c1 * 512;
    ushort* bL0 = Bs + c0 * 512;
    ushort* bL1 = Bs + c1 * 512;

    f32x4 acc[4][4];
#pragma unroll
    for (int i = 0; i < 4; ++i)
#pragma unroll
        for (int j = 0; j < 4; ++j)
            acc[i][j] = (f32x4){0.f, 0.f, 0.f, 0.f};

    for (int k0 = 0; k0 < K; k0 += 32) {
        __syncthreads();              // previous iteration's LDS reads done
        glds16(aG0 + k0, aL0);
        glds16(aG1 + k0, aL1);
        glds16(bG0 + k0, bL0);
        glds16(bG1 + k0, bL1);
        __syncthreads();              // vmcnt(0) drained before barrier

        short8 af[4], bfr[4];
#pragma unroll
        for (int mt = 0; mt < 4; ++mt)
            af[mt] = *(const short8*)(As + (wr * 64 + mt * 16 + l16) * 32 + quad * 8);
#pragma unroll
        for (int nt = 0; nt < 4; ++nt)
            bfr[nt] = *(const short8*)(Bs + (wc * 64 + nt * 16 + l16) * 32 + quad * 8);

#pragma unroll
        for (int mt = 0; mt < 4; ++mt)
#pragma unroll
            for (int nt = 0; nt < 4; ++nt)
                acc[mt][nt] = __builtin_amdgcn_mfma_f32_16x16x32_bf16(
                    af[mt], bfr[nt], acc[mt][nt], 0, 0, 0);
    }

    // epilogue: C[m,n] = acc + bias[n]
#pragma unroll
    for (int mt = 0; mt < 4; ++mt) {
#pragma unroll
        for (int nt = 0; nt < 4; ++nt) {
            const long n = nBase + wc * 64 + nt * 16 + l16;
            const float bv = bias[n];
#pragma unroll
            for (int r = 0; r < 4; ++r) {
                const long m = mBase + wr * 64 + mt * 16 + quad * 4 + r;
                if constexpr (std::is_same<OT, float>::value)
                    C[m * Nn + n] = acc[mt][nt][r] + bv;
                else
                    C[m * Nn + n] = f2b(acc[mt][nt][r] + bv);
            }
        }
    }
}

// ---------------------------------------------------------------------------
// Attention v2: one block (256 thr) pipelines PPB=8 consecutive positions.
//  - staging via global_load_lds (q/cq, k, v), double-buffered; mask reg-prefetch
//  - LDS stays LINEAR (glds requirement); bank conflicts avoided by
//    pre-swizzling the per-lane GLOBAL source column: slot(row,c) holds
//    global chunk (row, c ^ (row&7)); reads apply the same XOR (involution).
//  - softmax P kept in registers; PV uses __shfl broadcast within the
//    16-lane group (score thread (h,e) and PV thread (h,d) share a wave
//    16-group), eliminating the sc[] LDS round-trip and the mid barrier.
//  - ONE __syncthreads per position; its implicit vmcnt(0) drain waits on
//    glds issued a full compute-phase earlier (stage-early / consume-late).
// LDS: 3 tensors x 2 buffers x 4 KB = 24 KB -> 6 blocks/CU.
// ---------------------------------------------------------------------------
__global__ __launch_bounds__(256)
void attn_kernel(const float*  __restrict__ queries,   // (N,Sq,E) f32
                 const ushort* __restrict__ condfeat,  // (N,Sq,E) bf16
                 const float*  __restrict__ keys,      // (N,Skv,E) f32
                 const float*  __restrict__ values,    // (N,Skv,E) f32
                 const int*    __restrict__ mask,      // (N,Skv,16,16) i32
                 ushort* __restrict__ attout)          // (N,Skv,E) bf16
{
    __shared__ __attribute__((aligned(16))) float cqb[2][1024];
    __shared__ __attribute__((aligned(16))) float kb [2][1024];
    __shared__ __attribute__((aligned(16))) float vb [2][1024];

    const int tid  = threadIdx.x;
    const int wave = tid >> 6;
    const int lane = tid & 63;
    const int h    = tid >> 4;        // score row / PV output head
    const int e    = tid & 15;        // score col
    const int basePos = blockIdx.x * PPB;   // multiple of 8 -> parity = i&1

    // staging map (f32 tensors): LDS float4 slot #tid = (row=tid>>4, c4=tid&15)
    // <- global float4 (row, c4 ^ (row&7)).
    const int r   = tid >> 4;
    const int c4s = ((tid & 15) ^ (r & 7)) << 2;    // swizzled float offset in row

    auto stage = [&](int p, int b) {
        const size_t rowOff = ((size_t)p << 10) + (size_t)((r << 6) + c4s);
        glds16((const ushort*)(keys   + rowOff), (ushort*)&kb[b][wave << 8]);
        glds16((const ushort*)(values + rowOff), (ushort*)&vb[b][wave << 8]);
        const int n  = p >> 12;
        const int sh = (p & 4095) >> 1;
        if (p & 1) {
            // bf16 row (2 KB): 128 ushort8 chunks, waves 0-1 only
            if (tid < 128) {
                const int rr = tid >> 3, c8 = tid & 7;
                glds16(condfeat + (((size_t)n * SQ + sh) << 10)
                                + (size_t)((rr << 6) + ((c8 ^ (rr & 7)) << 3)),
                       (ushort*)&cqb[b][0] + (wave << 9));
            }
        } else {
            glds16((const ushort*)(queries + (((size_t)n * SQ + sh) << 10)
                                           + (size_t)((r << 6) + c4s)),
                   (ushort*)&cqb[b][wave << 8]);
        }
    };

    auto compute = [&](int p, int b, int mv) {
        // ---- scores: s[h][e] = dot(cq[h,:], k[e,:]) / 8 ----
        float s = 0.f;
        if (p & 1) {          // bf16 cq path (compile-time after unroll)
            const ushort* cq = (const ushort*)&cqb[b][0];
#pragma unroll
            for (int d8 = 0; d8 < 8; ++d8) {
                short8 qv = *(const short8*)(cq + (h << 6) + ((d8 ^ (h & 7)) << 3));
                float4 k0 = *(const float4*)&kb[b][(e << 6) + (((2 * d8)     ^ (e & 7)) << 2)];
                float4 k1 = *(const float4*)&kb[b][(e << 6) + (((2 * d8 + 1) ^ (e & 7)) << 2)];
                s += b2f((ushort)qv[0]) * k0.x + b2f((ushort)qv[1]) * k0.y
                   + b2f((ushort)qv[2]) * k0.z + b2f((ushort)qv[3]) * k0.w
                   + b2f((ushort)qv[4]) * k1.x + b2f((ushort)qv[5]) * k1.y
                   + b2f((ushort)qv[6]) * k1.z + b2f((ushort)qv[7]) * k1.w;
            }
        } else {              // f32 queries path
#pragma unroll
            for (int d4 = 0; d4 < 16; ++d4) {
                float4 qv = *(const float4*)&cqb[b][(h << 6) + ((d4 ^ (h & 7)) << 2)];
                float4 kv = *(const float4*)&kb [b][(e << 6) + ((d4 ^ (e & 7)) << 2)];
                s += qv.x * kv.x + qv.y * kv.y + qv.z * kv.z + qv.w * kv.w;
            }
        }
        s *= 0.125f;                                  // 1/sqrt(64)
        s = (mv == 0) ? -1e20f : s;

        // ---- softmax over e (16-lane group shuffle butterflies) ----
        float mx = s;
#pragma unroll
        for (int d = 1; d < 16; d <<= 1)
            mx = fmaxf(mx, __shfl_xor(mx, d));
        const float ex = __expf(s - mx);              // fully-masked row -> 1/16
        float sum = ex;
#pragma unroll
        for (int d = 1; d < 16; d <<= 1)
            sum += __shfl_xor(sum, d);
        const float pr = ex / sum;

        // ---- PV: out[h][(tid&15)*4 ..] = sum_e p[h][e] * v[e][d] ----
        // p[h][ee] lives in lane (lane&48)|ee of the same wave.
        f32x4 acc = (f32x4){0.f, 0.f, 0.f, 0.f};
        const int sb = lane & 48;
#pragma unroll
        for (int ee = 0; ee < 16; ++ee) {
            const float pe = __shfl(pr, sb | ee);
            float4 v4 = *(const float4*)&vb[b][(ee << 6) + (((tid & 15) ^ (ee & 7)) << 2)];
            acc[0] += pe * v4.x; acc[1] += pe * v4.y;
            acc[2] += pe * v4.z; acc[3] += pe * v4.w;
        }
        ushort4 o;
        o.x = f2b(acc[0]); o.y = f2b(acc[1]); o.z = f2b(acc[2]); o.w = f2b(acc[3]);
        *(ushort4*)(attout + ((size_t)p << 10) + (tid << 2)) = o;
    };

    // prologue
    stage(basePos, 0);
    int mvN = mask[((size_t)basePos << 8) + tid];
    __syncthreads();                                  // buffer 0 ready

#pragma unroll
    for (int i = 0; i < PPB; ++i) {
        const int mv = mvN;
        if (i + 1 < PPB) {
            stage(basePos + i + 1, (i + 1) & 1);      // prefetch into other buffer
            mvN = mask[((size_t)(basePos + i + 1) << 8) + tid];
        }
        compute(basePos + i, i & 1, mv);              // consume current buffer
        __syncthreads();   // reads of cur done; prefetched loads drained
    }
}

// ---------------------------------------------------------------------------
extern "C" void kernel_launch(void* const* d_in, const int* in_sizes, int n_in,
                              void* d_out, int out_size, void* d_ws, size_t ws_size,
                              hipStream_t stream)
{
    const float* values    = (const float*)d_in[0];
    const float* keys      = (const float*)d_in[1];
    const float* queries   = (const float*)d_in[2];
    const int*   mask      = (const int*)  d_in[3];
    const float* condition = (const float*)d_in[4];
    const float* Wc        = (const float*)d_in[5];
    const float* bc        = (const float*)d_in[6];
    const float* Wo        = (const float*)d_in[7];
    const float* bo        = (const float*)d_in[8];
    float* out = (float*)d_out;

    // workspace (48 MB total, with liveness-based aliasing):
    //  [0,16MB)  condfeat bf16 (8192x1024)      live: gemm1 -> attn
    //  [16,48MB) attout  bf16 (16384x1024)      live: attn -> gemm3
    //  cond_bf (8MB) + Wc_bf (1MB) alias attout (dead before attn writes it)
    //  Wo_bf (2MB) aliases condfeat (converted after attn, condfeat then dead)
    ushort* condfeat = (ushort*)d_ws;
    ushort* attout   = condfeat + (size_t)NB * SQ * EMB;
    ushort* cond_bf  = attout;
    ushort* Wc_bf    = attout + (size_t)NB * SQ * CDIM;
    ushort* Wo_bf    = condfeat;

    // converts needed before gemm1
    cvt_f32_bf16<<<(NB * SQ * CDIM / 4 + 255) / 256, 256, 0, stream>>>(
        condition, cond_bf, NB * SQ * CDIM / 4);
    cvt_f32_bf16<<<(EMB * CDIM / 4 + 255) / 256, 256, 0, stream>>>(
        Wc, Wc_bf, EMB * CDIM / 4);

    // 1) cond_feat = condition @ Wc^T + bc   (8192x1024, K=512) -> bf16
    {
        dim3 grid((NB * SQ) / 128, EMB / 128);
        gemm_bt_bias<ushort><<<grid, 256, 0, stream>>>(
            cond_bf, Wc_bf, bc, condfeat, NB * SQ, EMB, CDIM);
    }

    // 2) per-position 16x16 attention -> att_out (bf16), 8 positions/block
    attn_kernel<<<(NB * SKV) / PPB, 256, 0, stream>>>(queries, condfeat, keys,
                                                      values, mask, attout);

    // convert Wo after attn (aliases dead condfeat)
    cvt_f32_bf16<<<(EMB * EMB / 4 + 255) / 256, 256, 0, stream>>>(
        Wo, Wo_bf, EMB * EMB / 4);

    // 3) out = att_out @ Wo^T + bo   (16384x1024, K=1024) -> f32
    {
        dim3 grid((NB * SKV) / 128, EMB / 128);
        gemm_bt_bias<float><<<grid, 256, 0, stream>>>(
            attout, Wo_bf, bo, out, NB * SKV, EMB, EMB);
    }
}

// Round 2
// 311.809 us; speedup vs baseline: 1.0082x; 1.0082x over previous
//
#include <hip/hip_runtime.h>
#include <hip/hip_bf16.h>
#include <type_traits>

// Problem constants: N=4, Sq=2048, Skv=4096, E=1024, H=16, D=64, C=512
// Float tensors are FP32 in global; mask int32; output fp32.
#define NB   4
#define SQ   2048
#define SKV  4096
#define EMB  1024
#define CDIM 512
#define POS  4        // positions per attention block (register-prefetch pipeline)

typedef __attribute__((ext_vector_type(8))) short short8;
typedef __attribute__((ext_vector_type(4))) float f32x4;

__device__ __forceinline__ float b2f(ushort u) {
    union { unsigned int i; float f; } v;
    v.i = ((unsigned int)u) << 16;
    return v.f;
}
__device__ __forceinline__ ushort f2b(float f) {
    union { float f; unsigned int i; } v; v.f = f;
    unsigned int x = v.i;
    return (ushort)((x + 0x7fffu + ((x >> 16) & 1u)) >> 16);   // RNE
}

// async global->LDS, 16B per lane; LDS dest = wave-uniform base + lane*16
__device__ __forceinline__ void glds16(const ushort* gp, ushort* lp) {
    __builtin_amdgcn_global_load_lds(
        (const __attribute__((address_space(1))) unsigned int*)gp,
        (__attribute__((address_space(3))) unsigned int*)lp,
        16, 0, 0);
}

// ---------------------------------------------------------------------------
// f32 -> bf16 bulk convert (memory-bound, float4/ushort4)
// ---------------------------------------------------------------------------
__global__ __launch_bounds__(256)
void cvt_f32_bf16(const float* __restrict__ in, ushort* __restrict__ out, int n4)
{
    const int i = blockIdx.x * 256 + threadIdx.x;
    if (i < n4) {
        float4 v = ((const float4*)in)[i];
        ushort4 o;
        o.x = f2b(v.x); o.y = f2b(v.y); o.z = f2b(v.z); o.w = f2b(v.w);
        ((ushort4*)out)[i] = o;
    }
}

// ---------------------------------------------------------------------------
// Pure-bf16 GEMM (m97 structure): C[m,n] = sum_k A[m,k]*B[n,k] + bias[n]
// NEW this round: XCD-aware tile remap. With gy==8 N-tiles, consecutive
// blocks resident on one XCD now cover all 8 N-tiles of one M-tile, so the
// A-panel (256 KB) is served from that XCD's L2 instead of being re-fetched
// 8x from L3/HBM. Bijective for gx%8==0; identity fallback otherwise.
// ---------------------------------------------------------------------------
template <typename OT>
__global__ __launch_bounds__(256)
void gemm_bt_bias(const ushort* __restrict__ A, const ushort* __restrict__ B,
                  const float* __restrict__ bias, OT* __restrict__ C,
                  int M, int Nn, int K)
{
    __shared__ __attribute__((aligned(16))) ushort As[128 * 32];
    __shared__ __attribute__((aligned(16))) ushort Bs[128 * 32];

    const int tid  = threadIdx.x;
    const int wave = tid >> 6;
    const int lane = tid & 63;
    const int quad = lane >> 4;
    const int l16  = lane & 15;
    const int wr   = wave >> 1;   // wave row (64 rows of M)
    const int wc   = wave & 1;    // wave col (64 cols of N)

    // XCD-aware tile remap (dispatch round-robins consecutive flat ids
    // across the 8 XCDs; give XCD c a contiguous chunk of M-tiles, cycling
    // N-tiles innermost so the A-panel stays hot in that XCD's L2).
    int mTile, nTile;
    {
        const int gx = gridDim.x, gy = gridDim.y;
        const int flat = blockIdx.y * gx + blockIdx.x;
        if ((gx & 7) == 0 && gy == 8) {
            const int c = flat & 7, j = flat >> 3;
            mTile = c * (gx >> 3) + (j >> 3);
            nTile = j & 7;
        } else {
            mTile = blockIdx.x; nTile = blockIdx.y;
        }
    }
    const long mBase = (long)mTile * 128;
    const long nBase = (long)nTile * 128;

    const ushort* Ablk = A + mBase * K;
    const ushort* Bblk = B + nBase * K;

    const int lr = lane >> 2;
    const int lc = (lane & 3) * 8;
    const int c0 = wave * 2, c1 = wave * 2 + 1;
    const ushort* aG0 = Ablk + (long)(c0 * 16 + lr) * K + lc;
    const ushort* aG1 = Ablk + (long)(c1 * 16 + lr) * K + lc;
    const ushort* bG0 = Bblk + (long)(c0 * 16 + lr) * K + lc;
    const ushort* bG1 = Bblk + (long)(c1 * 16 + lr) * K + lc;
    ushort* aL0 = As + c0 * 512;
    ushort* aL1 = As + c1 * 512;
    ushort* bL0 = Bs + c0 * 512;
    ushort* bL1 = Bs + c1 * 512;

    f32x4 acc[4][4];
#pragma unroll
    for (int i = 0; i < 4; ++i)
#pragma unroll
        for (int j = 0; j < 4; ++j)
            acc[i][j] = (f32x4){0.f, 0.f, 0.f, 0.f};

    for (int k0 = 0; k0 < K; k0 += 32) {
        __syncthreads();              // previous iteration's LDS reads done
        glds16(aG0 + k0, aL0);
        glds16(aG1 + k0, aL1);
        glds16(bG0 + k0, bL0);
        glds16(bG1 + k0, bL1);
        __syncthreads();              // vmcnt(0) drained before barrier

        short8 af[4], bfr[4];
#pragma unroll
        for (int mt = 0; mt < 4; ++mt)
            af[mt] = *(const short8*)(As + (wr * 64 + mt * 16 + l16) * 32 + quad * 8);
#pragma unroll
        for (int nt = 0; nt < 4; ++nt)
            bfr[nt] = *(const short8*)(Bs + (wc * 64 + nt * 16 + l16) * 32 + quad * 8);

#pragma unroll
        for (int mt = 0; mt < 4; ++mt)
#pragma unroll
            for (int nt = 0; nt < 4; ++nt)
                acc[mt][nt] = __builtin_amdgcn_mfma_f32_16x16x32_bf16(
                    af[mt], bfr[nt], acc[mt][nt], 0, 0, 0);
    }

    // epilogue: C[m,n] = acc + bias[n]
#pragma unroll
    for (int mt = 0; mt < 4; ++mt) {
#pragma unroll
        for (int nt = 0; nt < 4; ++nt) {
            const long n = nBase + wc * 64 + nt * 16 + l16;
            const float bv = bias[n];
#pragma unroll
            for (int r = 0; r < 4; ++r) {
                const long m = mBase + wr * 64 + mt * 16 + quad * 4 + r;
                if constexpr (std::is_same<OT, float>::value)
                    C[m * Nn + n] = acc[mt][nt][r] + bv;
                else
                    C[m * Nn + n] = f2b(acc[mt][nt][r] + bv);
            }
        }
    }
}

// ---------------------------------------------------------------------------
// Attention v3: round-0 body kept byte-identical (padded-68 LDS rows, sc[]
// LDS softmax round-trip — 131K conflicts, negligible). One block now loops
// over POS=4 consecutive positions with REGISTER prefetch (T14): the next
// position's q/k/v/mask global loads are issued right after the staging
// barrier and consumed one full compute-phase later, so HBM latency hides
// under the current position's score+PV work. LDS stays 14 KB (single
// buffer -> same occupancy as round 0); blocks drop 16384 -> 4096.
// 3 barriers/position protect LDS reuse.
// ---------------------------------------------------------------------------
__global__ __launch_bounds__(256)
void attn_kernel(const float*  __restrict__ queries,   // (N,Sq,E) f32
                 const ushort* __restrict__ condfeat,  // (N,Sq,E) bf16
                 const float*  __restrict__ keys,      // (N,Skv,E) f32
                 const float*  __restrict__ values,    // (N,Skv,E) f32
                 const int*    __restrict__ mask,      // (N,Skv,16,16) i32
                 ushort* __restrict__ attout)          // (N,Skv,E) bf16
{
    const int tid     = threadIdx.x;
    const int basePos = blockIdx.x * POS;   // multiple of 4 -> parity = i&1

    __shared__ __attribute__((aligned(16))) float cq[16 * 68];
    __shared__ __attribute__((aligned(16))) float ks[16 * 68];
    __shared__ __attribute__((aligned(16))) float vs[16 * 68];
    __shared__ float sc[16 * 17];

    const int base4 = tid * 4;              // 4 elems/thread, 1024 total
    const int hs = base4 >> 6, dsd = base4 & 63;

    auto loadQ = [&](int p) -> float4 {
        const int n = p >> 12, sh = (p & 4095) >> 1;
        float4 q4;
        if (p & 1) {
            const ushort* cp = condfeat + ((size_t)n * SQ + sh) * EMB + base4;
            ushort4 c4 = *(const ushort4*)cp;
            q4.x = b2f(c4.x); q4.y = b2f(c4.y); q4.z = b2f(c4.z); q4.w = b2f(c4.w);
        } else {
            q4 = *(const float4*)(queries + ((size_t)n * SQ + sh) * EMB + base4);
        }
        return q4;
    };

    float4 q4 = loadQ(basePos);
    float4 k4 = *(const float4*)(keys   + ((size_t)basePos << 10) + base4);
    float4 v4 = *(const float4*)(values + ((size_t)basePos << 10) + base4);
    int    mv = mask[((size_t)basePos << 8) + tid];

#pragma unroll
    for (int i = 0; i < POS; ++i) {
        const int p = basePos + i;

        // stage current position from registers
        *(float4*)(cq + hs * 68 + dsd) = q4;
        *(float4*)(ks + hs * 68 + dsd) = k4;
        *(float4*)(vs + hs * 68 + dsd) = v4;
        __syncthreads();

        // issue next position's loads NOW; consumed after 2 more barriers
        float4 q4n, k4n, v4n; int mvn = 0;
        if (i + 1 < POS) {
            q4n = loadQ(p + 1);
            k4n = *(const float4*)(keys   + ((size_t)(p + 1) << 10) + base4);
            v4n = *(const float4*)(values + ((size_t)(p + 1) << 10) + base4);
            mvn = mask[((size_t)(p + 1) << 8) + tid];
        }

        // scores + shuffle softmax: thread (h = tid>>4, e = tid&15)
        {
            const int h = tid >> 4, e = tid & 15;
            float s = 0.f;
#pragma unroll
            for (int d = 0; d < 64; d += 4) {
                float4 a = *(const float4*)(cq + h * 68 + d);
                float4 b = *(const float4*)(ks + e * 68 + d);
                s += a.x * b.x + a.y * b.y + a.z * b.z + a.w * b.w;
            }
            s *= 0.125f;                                  // 1/sqrt(64)
            s = (mv == 0) ? -1e20f : s;

            float mx = s;
#pragma unroll
            for (int d = 1; d < 16; d <<= 1)
                mx = fmaxf(mx, __shfl_xor(mx, d));
            const float ex = __expf(s - mx);              // fully-masked row -> 1/16
            float sum = ex;
#pragma unroll
            for (int d = 1; d < 16; d <<= 1)
                sum += __shfl_xor(sum, d);
            sc[h * 17 + e] = ex / sum;
        }
        __syncthreads();

        // out[h,d0..d0+3] = sum_e p[h,e]*v[e,d]
        {
            float4 a = {0.f, 0.f, 0.f, 0.f};
#pragma unroll
            for (int e = 0; e < 16; ++e) {
                const float pe = sc[hs * 17 + e];
                float4 vv = *(const float4*)(vs + e * 68 + dsd);
                a.x += pe * vv.x; a.y += pe * vv.y;
                a.z += pe * vv.z; a.w += pe * vv.w;
            }
            ushort4 o;
            o.x = f2b(a.x); o.y = f2b(a.y); o.z = f2b(a.z); o.w = f2b(a.w);
            *(ushort4*)(attout + ((size_t)p << 10) + base4) = o;
        }

        if (i + 1 < POS) {
            __syncthreads();          // PV reads done before LDS overwrite
            q4 = q4n; k4 = k4n; v4 = v4n; mv = mvn;
        }
    }
}

// ---------------------------------------------------------------------------
extern "C" void kernel_launch(void* const* d_in, const int* in_sizes, int n_in,
                              void* d_out, int out_size, void* d_ws, size_t ws_size,
                              hipStream_t stream)
{
    const float* values    = (const float*)d_in[0];
    const float* keys      = (const float*)d_in[1];
    const float* queries   = (const float*)d_in[2];
    const int*   mask      = (const int*)  d_in[3];
    const float* condition = (const float*)d_in[4];
    const float* Wc        = (const float*)d_in[5];
    const float* bc        = (const float*)d_in[6];
    const float* Wo        = (const float*)d_in[7];
    const float* bo        = (const float*)d_in[8];
    float* out = (float*)d_out;

    // workspace (48 MB total, with liveness-based aliasing):
    //  [0,16MB)  condfeat bf16 (8192x1024)      live: gemm1 -> attn
    //  [16,48MB) attout  bf16 (16384x1024)      live: attn -> gemm3
    //  cond_bf (8MB) + Wc_bf (1MB) alias attout (dead before attn writes it)
    //  Wo_bf (2MB) aliases condfeat (converted after attn, condfeat then dead)
    ushort* condfeat = (ushort*)d_ws;
    ushort* attout   = condfeat + (size_t)NB * SQ * EMB;
    ushort* cond_bf  = attout;
    ushort* Wc_bf    = attout + (size_t)NB * SQ * CDIM;
    ushort* Wo_bf    = condfeat;

    // converts needed before gemm1
    cvt_f32_bf16<<<(NB * SQ * CDIM / 4 + 255) / 256, 256, 0, stream>>>(
        condition, cond_bf, NB * SQ * CDIM / 4);
    cvt_f32_bf16<<<(EMB * CDIM / 4 + 255) / 256, 256, 0, stream>>>(
        Wc, Wc_bf, EMB * CDIM / 4);

    // 1) cond_feat = condition @ Wc^T + bc   (8192x1024, K=512) -> bf16
    {
        dim3 grid((NB * SQ) / 128, EMB / 128);
        gemm_bt_bias<ushort><<<grid, 256, 0, stream>>>(
            cond_bf, Wc_bf, bc, condfeat, NB * SQ, EMB, CDIM);
    }

    // 2) per-position 16x16 attention -> att_out (bf16), 4 positions/block
    attn_kernel<<<(NB * SKV) / POS, 256, 0, stream>>>(queries, condfeat, keys,
                                                      values, mask, attout);

    // convert Wo after attn (aliases dead condfeat)
    cvt_f32_bf16<<<(EMB * EMB / 4 + 255) / 256, 256, 0, stream>>>(
        Wo, Wo_bf, EMB * EMB / 4);

    // 3) out = att_out @ Wo^T + bo   (16384x1024, K=1024) -> f32
    {
        dim3 grid((NB * SKV) / 128, EMB / 128);
        gemm_bt_bias<float><<<grid, 256, 0, stream>>>(
            attout, Wo_bf, bo, out, NB * SKV, EMB, EMB);
    }
}

// Round 3
// 301.623 us; speedup vs baseline: 1.0422x; 1.0338x over previous
//
#include <hip/hip_runtime.h>
#include <hip/hip_bf16.h>
#include <type_traits>

// Problem constants: N=4, Sq=2048, Skv=4096, E=1024, H=16, D=64, C=512
// Float tensors are FP32 in global; mask int32; output fp32.
#define NB   4
#define SQ   2048
#define SKV  4096
#define EMB  1024
#define CDIM 512

typedef __attribute__((ext_vector_type(8))) short short8;
typedef __attribute__((ext_vector_type(4))) float f32x4;

__device__ __forceinline__ float b2f(ushort u) {
    union { unsigned int i; float f; } v;
    v.i = ((unsigned int)u) << 16;
    return v.f;
}
__device__ __forceinline__ ushort f2b(float f) {
    union { float f; unsigned int i; } v; v.f = f;
    unsigned int x = v.i;
    return (ushort)((x + 0x7fffu + ((x >> 16) & 1u)) >> 16);   // RNE
}

// async global->LDS, 16B per lane; LDS dest = wave-uniform base + lane*16
__device__ __forceinline__ void glds16(const ushort* gp, ushort* lp) {
    __builtin_amdgcn_global_load_lds(
        (const __attribute__((address_space(1))) unsigned int*)gp,
        (__attribute__((address_space(3))) unsigned int*)lp,
        16, 0, 0);
}

// ---------------------------------------------------------------------------
// f32 -> bf16 bulk convert (memory-bound, float4/ushort4)
// ---------------------------------------------------------------------------
__global__ __launch_bounds__(256)
void cvt_f32_bf16(const float* __restrict__ in, ushort* __restrict__ out, int n4)
{
    const int i = blockIdx.x * 256 + threadIdx.x;
    if (i < n4) {
        float4 v = ((const float4*)in)[i];
        ushort4 o;
        o.x = f2b(v.x); o.y = f2b(v.y); o.z = f2b(v.z); o.w = f2b(v.w);
        ((ushort4*)out)[i] = o;
    }
}

// ---------------------------------------------------------------------------
// Pure-bf16 GEMM (m97 structure): C[m,n] = sum_k A[m,k]*B[n,k] + bias[n]
// XCD-aware tile remap kept from last round (neutral-to-slightly-positive).
// ---------------------------------------------------------------------------
template <typename OT>
__global__ __launch_bounds__(256)
void gemm_bt_bias(const ushort* __restrict__ A, const ushort* __restrict__ B,
                  const float* __restrict__ bias, OT* __restrict__ C,
                  int M, int Nn, int K)
{
    __shared__ __attribute__((aligned(16))) ushort As[128 * 32];
    __shared__ __attribute__((aligned(16))) ushort Bs[128 * 32];

    const int tid  = threadIdx.x;
    const int wave = tid >> 6;
    const int lane = tid & 63;
    const int quad = lane >> 4;
    const int l16  = lane & 15;
    const int wr   = wave >> 1;   // wave row (64 rows of M)
    const int wc   = wave & 1;    // wave col (64 cols of N)

    int mTile, nTile;
    {
        const int gx = gridDim.x, gy = gridDim.y;
        const int flat = blockIdx.y * gx + blockIdx.x;
        if ((gx & 7) == 0 && gy == 8) {
            const int c = flat & 7, j = flat >> 3;
            mTile = c * (gx >> 3) + (j >> 3);
            nTile = j & 7;
        } else {
            mTile = blockIdx.x; nTile = blockIdx.y;
        }
    }
    const long mBase = (long)mTile * 128;
    const long nBase = (long)nTile * 128;

    const ushort* Ablk = A + mBase * K;
    const ushort* Bblk = B + nBase * K;

    const int lr = lane >> 2;
    const int lc = (lane & 3) * 8;
    const int c0 = wave * 2, c1 = wave * 2 + 1;
    const ushort* aG0 = Ablk + (long)(c0 * 16 + lr) * K + lc;
    const ushort* aG1 = Ablk + (long)(c1 * 16 + lr) * K + lc;
    const ushort* bG0 = Bblk + (long)(c0 * 16 + lr) * K + lc;
    const ushort* bG1 = Bblk + (long)(c1 * 16 + lr) * K + lc;
    ushort* aL0 = As + c0 * 512;
    ushort* aL1 = As + c1 * 512;
    ushort* bL0 = Bs + c0 * 512;
    ushort* bL1 = Bs + c1 * 512;

    f32x4 acc[4][4];
#pragma unroll
    for (int i = 0; i < 4; ++i)
#pragma unroll
        for (int j = 0; j < 4; ++j)
            acc[i][j] = (f32x4){0.f, 0.f, 0.f, 0.f};

    for (int k0 = 0; k0 < K; k0 += 32) {
        __syncthreads();              // previous iteration's LDS reads done
        glds16(aG0 + k0, aL0);
        glds16(aG1 + k0, aL1);
        glds16(bG0 + k0, bL0);
        glds16(bG1 + k0, bL1);
        __syncthreads();              // vmcnt(0) drained before barrier

        short8 af[4], bfr[4];
#pragma unroll
        for (int mt = 0; mt < 4; ++mt)
            af[mt] = *(const short8*)(As + (wr * 64 + mt * 16 + l16) * 32 + quad * 8);
#pragma unroll
        for (int nt = 0; nt < 4; ++nt)
            bfr[nt] = *(const short8*)(Bs + (wc * 64 + nt * 16 + l16) * 32 + quad * 8);

#pragma unroll
        for (int mt = 0; mt < 4; ++mt)
#pragma unroll
            for (int nt = 0; nt < 4; ++nt)
                acc[mt][nt] = __builtin_amdgcn_mfma_f32_16x16x32_bf16(
                    af[mt], bfr[nt], acc[mt][nt], 0, 0, 0);
    }

    // epilogue: C[m,n] = acc + bias[n]
#pragma unroll
    for (int mt = 0; mt < 4; ++mt) {
#pragma unroll
        for (int nt = 0; nt < 4; ++nt) {
            const long n = nBase + wc * 64 + nt * 16 + l16;
            const float bv = bias[n];
#pragma unroll
            for (int r = 0; r < 4; ++r) {
                const long m = mBase + wr * 64 + mt * 16 + quad * 4 + r;
                if constexpr (std::is_same<OT, float>::value)
                    C[m * Nn + n] = acc[mt][nt][r] + bv;
                else
                    C[m * Nn + n] = f2b(acc[mt][nt][r] + bv);
            }
        }
    }
}

// ---------------------------------------------------------------------------
// Attention v4 (MFMA): ONE WAVE per position, barrier-free. The R0 VALU body
// was LDS-throughput-bound (~76 LDS insts/thread/pos ≈ 180K LDS-pipe
// cycles/CU ≈ 75 µs — matches measured dur). MFMA replaces the dot products:
//   S^T(16e x 16h) = K(16x64) . CQ(16x64)^B   -> 2x mfma_16x16x32_bf16
//   O (16h x 64d)  = V^T-slices . P            -> 4x mfma (K=32, e>=16 zero)
// Fragment layouts derived from the verified gemm kernel:
//   A/B-frag: lane holds M/N-row (lane&15), k = quad*8+j (j=0..7)
//   C/D:      col = lane&15, row = quad*4 + r
// CQ/K frags load GLOBAL->REG directly (no LDS); mask is 1 dwordx4/lane in
// exactly the S^T lane layout; softmax = 3 in-lane fmax + shfl_xor(16,32);
// P transpose into B-frag layout = 4 __shfl + cndmask (no LDS, no branch).
// Only V is LDS-staged (4 glds16, linear, wave-private -> no __syncthreads,
// just s_waitcnt vmcnt(0)); its column reads are 2-way/broadcast bank-safe.
// ---------------------------------------------------------------------------
__global__ __launch_bounds__(256)
void attn_kernel(const float*  __restrict__ queries,   // (N,Sq,E) f32
                 const ushort* __restrict__ condfeat,  // (N,Sq,E) bf16
                 const float*  __restrict__ keys,      // (N,Skv,E) f32
                 const float*  __restrict__ values,    // (N,Skv,E) f32
                 const int*    __restrict__ mask,      // (N,Skv,16,16) i32
                 ushort* __restrict__ attout)          // (N,Skv,E) bf16
{
    __shared__ __attribute__((aligned(16))) float vbuf[4][1024];

    const int tid  = threadIdx.x;
    const int wave = tid >> 6;
    const int lane = tid & 63;
    const int l15  = lane & 15;
    const int quad = lane >> 4;
    const int p    = blockIdx.x * 4 + wave;     // one position per wave
    const int n    = p >> 12;
    const int sh   = (p & 4095) >> 1;

    // ---- stage V (f32, 4KB) into wave-private LDS: linear identity map ----
    float* vb = vbuf[wave];
    const float* vrow = values + ((size_t)p << 10);
#pragma unroll
    for (int c = 0; c < 4; ++c)
        glds16((const ushort*)(vrow + c * 256 + lane * 4),
               (ushort*)(vb + c * 256));

    // ---- mask in S^T lane layout: (h=l15, e=quad*4+r) -> 1 dwordx4 ----
    const int4 mv = *(const int4*)(mask + ((size_t)p << 8) + l15 * 16 + quad * 4);

    union SU { short8 v; ushort u[8]; uint w[4]; };

    // ---- K A-frag: lane holds K[e=l15][d=quad*8+j], two K=32 halves ----
    const float* krow = keys + ((size_t)p << 10);
    SU ka, kb;
    {
        float kf[16];
        *(float4*)&kf[0]  = *(const float4*)(krow + l15 * 64 + quad * 8);
        *(float4*)&kf[4]  = *(const float4*)(krow + l15 * 64 + quad * 8 + 4);
        *(float4*)&kf[8]  = *(const float4*)(krow + l15 * 64 + 32 + quad * 8);
        *(float4*)&kf[12] = *(const float4*)(krow + l15 * 64 + 32 + quad * 8 + 4);
#pragma unroll
        for (int j = 0; j < 8; ++j) { ka.u[j] = f2b(kf[j]); kb.u[j] = f2b(kf[8 + j]); }
    }

    // ---- CQ B-frag: lane holds CQ[h=l15][d=quad*8+j] (f32 or bf16 source) ----
    SU qa, qb;
    if (p & 1) {
        const ushort* crow = condfeat + (((size_t)n * SQ + sh) << 10);
        qa.v = *(const short8*)(crow + l15 * 64 + quad * 8);
        qb.v = *(const short8*)(crow + l15 * 64 + 32 + quad * 8);
    } else {
        const float* qrow = queries + (((size_t)n * SQ + sh) << 10);
        float qf[16];
        *(float4*)&qf[0]  = *(const float4*)(qrow + l15 * 64 + quad * 8);
        *(float4*)&qf[4]  = *(const float4*)(qrow + l15 * 64 + quad * 8 + 4);
        *(float4*)&qf[8]  = *(const float4*)(qrow + l15 * 64 + 32 + quad * 8);
        *(float4*)&qf[12] = *(const float4*)(qrow + l15 * 64 + 32 + quad * 8 + 4);
#pragma unroll
        for (int j = 0; j < 8; ++j) { qa.u[j] = f2b(qf[j]); qb.u[j] = f2b(qf[8 + j]); }
    }

    // ---- scores: S^T = K . CQ  (D: lane holds S[h=l15][e=quad*4+r]) ----
    f32x4 sacc = (f32x4){0.f, 0.f, 0.f, 0.f};
    sacc = __builtin_amdgcn_mfma_f32_16x16x32_bf16(ka.v, qa.v, sacc, 0, 0, 0);
    sacc = __builtin_amdgcn_mfma_f32_16x16x32_bf16(kb.v, qb.v, sacc, 0, 0, 0);

    float s0 = (mv.x == 0) ? -1e20f : sacc[0] * 0.125f;
    float s1 = (mv.y == 0) ? -1e20f : sacc[1] * 0.125f;
    float s2 = (mv.z == 0) ? -1e20f : sacc[2] * 0.125f;
    float s3 = (mv.w == 0) ? -1e20f : sacc[3] * 0.125f;

    // ---- softmax over e: in-lane (4 e's) then cross-quad shfl_xor ----
    float mx = fmaxf(fmaxf(s0, s1), fmaxf(s2, s3));
    mx = fmaxf(mx, __shfl_xor(mx, 16));
    mx = fmaxf(mx, __shfl_xor(mx, 32));
    const float e0 = __expf(s0 - mx), e1 = __expf(s1 - mx);
    const float e2 = __expf(s2 - mx), e3 = __expf(s3 - mx);
    float sum = e0 + e1 + e2 + e3;
    sum += __shfl_xor(sum, 16);
    sum += __shfl_xor(sum, 32);
    const float inv = 1.f / sum;                 // fully-masked row -> 1/16

    // pack P[e][h] pairs (r=0,1) and (r=2,3) as bf16x2 words
    const uint pk01 = (uint)f2b(e0 * inv) | ((uint)f2b(e1 * inv) << 16);
    const uint pk23 = (uint)f2b(e2 * inv) | ((uint)f2b(e3 * inv) << 16);

    // ---- transpose P into B-frag layout: lane holds P[h=l15][e=quad*8+j],
    //      j=0..7; e>=16 (lanes 32-63) zero-padded (K=32 mfma). Source word
    //      for dest (quad_d, word W): lane quad_d*32 + (W>=2)*16 + l15,
    //      value pk01 (W even) / pk23 (W odd). 4 shuffles, no LDS buffer.
    const int srcA = (quad * 32 + l15) & 63;
    const int srcB = (quad * 32 + 16 + l15) & 63;
    SU pf;
    {
        const uint w0 = (uint)__shfl((int)pk01, srcA);
        const uint w1 = (uint)__shfl((int)pk23, srcA);
        const uint w2 = (uint)__shfl((int)pk01, srcB);
        const uint w3 = (uint)__shfl((int)pk23, srcB);
        const bool lo = (lane < 32);
        pf.w[0] = lo ? w0 : 0u; pf.w[1] = lo ? w1 : 0u;
        pf.w[2] = lo ? w2 : 0u; pf.w[3] = lo ? w3 : 0u;
    }

    // ---- V staged: wave-private glds -> only need vmcnt(0), no barrier ----
    asm volatile("s_waitcnt vmcnt(0)" ::: "memory");

    // ---- PV: per d-slice, A = V^T (lane: V[e=quad*8+j][d0+l15], quads 2,3
    //      mirror rows 0-15 — multiplied by pf's zeros), B = P.
    //      D: lane holds O[h=l15][d0 + quad*4 + r] -> 1 ushort4 store/slice.
    ushort* orow = attout + ((size_t)p << 10);
    const int eb = (quad & 1) * 8;
#pragma unroll
    for (int sl = 0; sl < 4; ++sl) {
        const int d0 = sl * 16;
        SU vf;
#pragma unroll
        for (int j = 0; j < 8; ++j)
            vf.u[j] = f2b(vb[(eb + j) * 64 + d0 + l15]);
        f32x4 oacc = (f32x4){0.f, 0.f, 0.f, 0.f};
        oacc = __builtin_amdgcn_mfma_f32_16x16x32_bf16(vf.v, pf.v, oacc, 0, 0, 0);
        ushort4 o;
        o.x = f2b(oacc[0]); o.y = f2b(oacc[1]);
        o.z = f2b(oacc[2]); o.w = f2b(oacc[3]);
        *(ushort4*)(orow + l15 * 64 + d0 + quad * 4) = o;
    }
}

// ---------------------------------------------------------------------------
extern "C" void kernel_launch(void* const* d_in, const int* in_sizes, int n_in,
                              void* d_out, int out_size, void* d_ws, size_t ws_size,
                              hipStream_t stream)
{
    const float* values    = (const float*)d_in[0];
    const float* keys      = (const float*)d_in[1];
    const float* queries   = (const float*)d_in[2];
    const int*   mask      = (const int*)  d_in[3];
    const float* condition = (const float*)d_in[4];
    const float* Wc        = (const float*)d_in[5];
    const float* bc        = (const float*)d_in[6];
    const float* Wo        = (const float*)d_in[7];
    const float* bo        = (const float*)d_in[8];
    float* out = (float*)d_out;

    // workspace (48 MB total, with liveness-based aliasing):
    //  [0,16MB)  condfeat bf16 (8192x1024)      live: gemm1 -> attn
    //  [16,48MB) attout  bf16 (16384x1024)      live: attn -> gemm3
    //  cond_bf (8MB) + Wc_bf (1MB) alias attout (dead before attn writes it)
    //  Wo_bf (2MB) aliases condfeat (converted after attn, condfeat then dead)
    ushort* condfeat = (ushort*)d_ws;
    ushort* attout   = condfeat + (size_t)NB * SQ * EMB;
    ushort* cond_bf  = attout;
    ushort* Wc_bf    = attout + (size_t)NB * SQ * CDIM;
    ushort* Wo_bf    = condfeat;

    // converts needed before gemm1
    cvt_f32_bf16<<<(NB * SQ * CDIM / 4 + 255) / 256, 256, 0, stream>>>(
        condition, cond_bf, NB * SQ * CDIM / 4);
    cvt_f32_bf16<<<(EMB * CDIM / 4 + 255) / 256, 256, 0, stream>>>(
        Wc, Wc_bf, EMB * CDIM / 4);

    // 1) cond_feat = condition @ Wc^T + bc   (8192x1024, K=512) -> bf16
    {
        dim3 grid((NB * SQ) / 128, EMB / 128);
        gemm_bt_bias<ushort><<<grid, 256, 0, stream>>>(
            cond_bf, Wc_bf, bc, condfeat, NB * SQ, EMB, CDIM);
    }

    // 2) per-position 16x16 attention -> att_out (bf16), 1 position/wave
    attn_kernel<<<(NB * SKV) / 4, 256, 0, stream>>>(queries, condfeat, keys,
                                                    values, mask, attout);

    // convert Wo after attn (aliases dead condfeat)
    cvt_f32_bf16<<<(EMB * EMB / 4 + 255) / 256, 256, 0, stream>>>(
        Wo, Wo_bf, EMB * EMB / 4);

    // 3) out = att_out @ Wo^T + bo   (16384x1024, K=1024) -> f32
    {
        dim3 grid((NB * SKV) / 128, EMB / 128);
        gemm_bt_bias<float><<<grid, 256, 0, stream>>>(
            attout, Wo_bf, bo, out, NB * SKV, EMB, EMB);
    }
}

// Round 4
// 287.295 us; speedup vs baseline: 1.0942x; 1.0499x over previous
//
#include <hip/hip_runtime.h>
#include <hip/hip_bf16.h>
#include <type_traits>

// Problem constants: N=4, Sq=2048, Skv=4096, E=1024, H=16, D=64, C=512
// Float tensors are FP32 in global; mask int32; output fp32.
#define NB   4
#define SQ   2048
#define SKV  4096
#define EMB  1024
#define CDIM 512
#define POSB 4        // positions per attention block (block-cooperative staging)

typedef __attribute__((ext_vector_type(8))) short short8;
typedef __attribute__((ext_vector_type(4))) float f32x4;
typedef __attribute__((ext_vector_type(4))) uint  u32x4;
typedef __attribute__((ext_vector_type(2))) uint  u32x2;

__device__ __forceinline__ float b2f(ushort u) {
    union { unsigned int i; float f; } v;
    v.i = ((unsigned int)u) << 16;
    return v.f;
}
__device__ __forceinline__ ushort f2b(float f) {
    union { float f; unsigned int i; } v; v.f = f;
    unsigned int x = v.i;
    return (ushort)((x + 0x7fffu + ((x >> 16) & 1u)) >> 16);   // RNE
}
// two bf16x2 words from a float4 (RNE, same numerics as f2b per element)
__device__ __forceinline__ u32x2 cvt2(f32x4 v) {
    u32x2 r;
    r[0] = (uint)f2b(v[0]) | ((uint)f2b(v[1]) << 16);
    r[1] = (uint)f2b(v[2]) | ((uint)f2b(v[3]) << 16);
    return r;
}

// async global->LDS, 16B per lane; LDS dest = wave-uniform base + lane*16
__device__ __forceinline__ void glds16(const ushort* gp, ushort* lp) {
    __builtin_amdgcn_global_load_lds(
        (const __attribute__((address_space(1))) unsigned int*)gp,
        (__attribute__((address_space(3))) unsigned int*)lp,
        16, 0, 0);
}

// ---------------------------------------------------------------------------
// f32 -> bf16 bulk convert (memory-bound, float4/ushort4)
// ---------------------------------------------------------------------------
__global__ __launch_bounds__(256)
void cvt_f32_bf16(const float* __restrict__ in, ushort* __restrict__ out, int n4)
{
    const int i = blockIdx.x * 256 + threadIdx.x;
    if (i < n4) {
        float4 v = ((const float4*)in)[i];
        ushort4 o;
        o.x = f2b(v.x); o.y = f2b(v.y); o.z = f2b(v.z); o.w = f2b(v.w);
        ((ushort4*)out)[i] = o;
    }
}

// ---------------------------------------------------------------------------
// Pure-bf16 GEMM (m97 structure): C[m,n] = sum_k A[m,k]*B[n,k] + bias[n]
// XCD-aware tile remap kept (neutral-to-slightly-positive).
// ---------------------------------------------------------------------------
template <typename OT>
__global__ __launch_bounds__(256)
void gemm_bt_bias(const ushort* __restrict__ A, const ushort* __restrict__ B,
                  const float* __restrict__ bias, OT* __restrict__ C,
                  int M, int Nn, int K)
{
    __shared__ __attribute__((aligned(16))) ushort As[128 * 32];
    __shared__ __attribute__((aligned(16))) ushort Bs[128 * 32];

    const int tid  = threadIdx.x;
    const int wave = tid >> 6;
    const int lane = tid & 63;
    const int quad = lane >> 4;
    const int l16  = lane & 15;
    const int wr   = wave >> 1;   // wave row (64 rows of M)
    const int wc   = wave & 1;    // wave col (64 cols of N)

    int mTile, nTile;
    {
        const int gx = gridDim.x, gy = gridDim.y;
        const int flat = blockIdx.y * gx + blockIdx.x;
        if ((gx & 7) == 0 && gy == 8) {
            const int c = flat & 7, j = flat >> 3;
            mTile = c * (gx >> 3) + (j >> 3);
            nTile = j & 7;
        } else {
            mTile = blockIdx.x; nTile = blockIdx.y;
        }
    }
    const long mBase = (long)mTile * 128;
    const long nBase = (long)nTile * 128;

    const ushort* Ablk = A + mBase * K;
    const ushort* Bblk = B + nBase * K;

    const int lr = lane >> 2;
    const int lc = (lane & 3) * 8;
    const int c0 = wave * 2, c1 = wave * 2 + 1;
    const ushort* aG0 = Ablk + (long)(c0 * 16 + lr) * K + lc;
    const ushort* aG1 = Ablk + (long)(c1 * 16 + lr) * K + lc;
    const ushort* bG0 = Bblk + (long)(c0 * 16 + lr) * K + lc;
    const ushort* bG1 = Bblk + (long)(c1 * 16 + lr) * K + lc;
    ushort* aL0 = As + c0 * 512;
    ushort* aL1 = As + c1 * 512;
    ushort* bL0 = Bs + c0 * 512;
    ushort* bL1 = Bs + c1 * 512;

    f32x4 acc[4][4];
#pragma unroll
    for (int i = 0; i < 4; ++i)
#pragma unroll
        for (int j = 0; j < 4; ++j)
            acc[i][j] = (f32x4){0.f, 0.f, 0.f, 0.f};

    for (int k0 = 0; k0 < K; k0 += 32) {
        __syncthreads();              // previous iteration's LDS reads done
        glds16(aG0 + k0, aL0);
        glds16(aG1 + k0, aL1);
        glds16(bG0 + k0, bL0);
        glds16(bG1 + k0, bL1);
        __syncthreads();              // vmcnt(0) drained before barrier

        short8 af[4], bfr[4];
#pragma unroll
        for (int mt = 0; mt < 4; ++mt)
            af[mt] = *(const short8*)(As + (wr * 64 + mt * 16 + l16) * 32 + quad * 8);
#pragma unroll
        for (int nt = 0; nt < 4; ++nt)
            bfr[nt] = *(const short8*)(Bs + (wc * 64 + nt * 16 + l16) * 32 + quad * 8);

#pragma unroll
        for (int mt = 0; mt < 4; ++mt)
#pragma unroll
            for (int nt = 0; nt < 4; ++nt)
                acc[mt][nt] = __builtin_amdgcn_mfma_f32_16x16x32_bf16(
                    af[mt], bfr[nt], acc[mt][nt], 0, 0, 0);
    }

    // epilogue: C[m,n] = acc + bias[n]
#pragma unroll
    for (int mt = 0; mt < 4; ++mt) {
#pragma unroll
        for (int nt = 0; nt < 4; ++nt) {
            const long n = nBase + wc * 64 + nt * 16 + l16;
            const float bv = bias[n];
#pragma unroll
            for (int r = 0; r < 4; ++r) {
                const long m = mBase + wr * 64 + mt * 16 + quad * 4 + r;
                if constexpr (std::is_same<OT, float>::value)
                    C[m * Nn + n] = acc[mt][nt][r] + bv;
                else
                    C[m * Nn + n] = f2b(acc[mt][nt][r] + bv);
            }
        }
    }
}

// ---------------------------------------------------------------------------
// Attention v5: HBM-RATE-bound fix. All 4 rounds show dur == 134MB/hbm_gbps
// with rate stuck at ~1.9 TB/s — the limiter is transaction quality, not any
// pipe. One block = POSB=4 consecutive positions:
//  - STAGE (block-cooperative, fully coalesced): K panel 16KB, V 16KB,
//    queries 8KB, condfeat 4KB as contiguous 4KB-per-instruction loads
//    (nontemporal: all read-once), converted f32->bf16 in-register, written
//    to PADDED bf16 LDS (row stride 68 ushorts; reg-staging frees us from
//    the glds linear-dest rule, so padding is legal; frag reads <=4-way).
//  - ONE barrier.
//  - COMPUTE: the verified v4 MFMA body per wave (S^T = K.CQ 2x mfma,
//    shuffle softmax, 4-shuffle P transpose, 4x PV mfma), fragments read as
//    ds_read_b64 pairs straight from bf16 LDS — zero f2b in the hot path,
//    no parity branch (Q pre-staged uniformly).
//  - STORE: O bounced through the dead Q LDS region (wave-private, LDS is
//    in-order per wave -> no barrier), then written as two contiguous 1KB
//    store instructions per position (was 64-lines-at-8B scatter).
// Numerics bit-identical to v4 (same f2b at the same points).
// LDS 3x8704B = 25.5KB -> ~6 blocks/CU.
// ---------------------------------------------------------------------------
__global__ __launch_bounds__(256)
void attn_kernel(const float*  __restrict__ queries,   // (N,Sq,E) f32
                 const ushort* __restrict__ condfeat,  // (N,Sq,E) bf16
                 const float*  __restrict__ keys,      // (N,Skv,E) f32
                 const float*  __restrict__ values,    // (N,Skv,E) f32
                 const int*    __restrict__ mask,      // (N,Skv,16,16) i32
                 ushort* __restrict__ attout)          // (N,Skv,E) bf16
{
    // bf16 tiles, row stride 68 ushorts (136B, 8B-aligned rows), 16 rows/pos
    __shared__ __attribute__((aligned(16))) ushort Kl[POSB * 1088];
    __shared__ __attribute__((aligned(16))) ushort Vl[POSB * 1088];
    __shared__ __attribute__((aligned(16))) ushort Ql[POSB * 1088];  // O reuses

    const int tid  = threadIdx.x;
    const int wave = tid >> 6;
    const int lane = tid & 63;
    const int l15  = lane & 15;
    const int quad = lane >> 4;
    const int p0   = blockIdx.x * POSB;         // even, same n for all 4
    const int n    = p0 >> 12;
    const int sh0  = (p0 & 4095) >> 1;          // query/cond rows sh0, sh0+1
    const int p    = p0 + wave;                 // this wave's position

    // ---------------- STAGE: issue all global loads back-to-back ----------
    const f32x4* kg = (const f32x4*)(keys    + ((size_t)p0 << 10)) + tid;
    const f32x4* vg = (const f32x4*)(values  + ((size_t)p0 << 10)) + tid;
    const f32x4* qg = (const f32x4*)(queries + (((size_t)n * SQ + sh0) << 10)) + tid;
    const u32x4* cg = (const u32x4*)(condfeat + (((size_t)n * SQ + sh0) << 10)) + tid;

    f32x4 kv0 = __builtin_nontemporal_load(kg);
    f32x4 kv1 = __builtin_nontemporal_load(kg + 256);
    f32x4 kv2 = __builtin_nontemporal_load(kg + 512);
    f32x4 kv3 = __builtin_nontemporal_load(kg + 768);
    f32x4 vv0 = __builtin_nontemporal_load(vg);
    f32x4 vv1 = __builtin_nontemporal_load(vg + 256);
    f32x4 vv2 = __builtin_nontemporal_load(vg + 512);
    f32x4 vv3 = __builtin_nontemporal_load(vg + 768);
    f32x4 qv0 = __builtin_nontemporal_load(qg);
    f32x4 qv1 = __builtin_nontemporal_load(qg + 256);
    u32x4 cv  = __builtin_nontemporal_load(cg);
    u32x4 mv  = __builtin_nontemporal_load(
        (const u32x4*)(mask + ((size_t)p << 8)) + (l15 * 4 + quad));

    // f32 staging map: flat float idx F = it*1024 + tid*4 -> pos=it (K/V) or
    // pos=2*it (queries), e = tid>>4, d = (tid&15)*4
    const int eo = (tid >> 4) * 68 + (tid & 15) * 4;
    *(u32x2*)(Kl + 0 * 1088 + eo) = cvt2(kv0);
    *(u32x2*)(Kl + 1 * 1088 + eo) = cvt2(kv1);
    *(u32x2*)(Kl + 2 * 1088 + eo) = cvt2(kv2);
    *(u32x2*)(Kl + 3 * 1088 + eo) = cvt2(kv3);
    *(u32x2*)(Vl + 0 * 1088 + eo) = cvt2(vv0);
    *(u32x2*)(Vl + 1 * 1088 + eo) = cvt2(vv1);
    *(u32x2*)(Vl + 2 * 1088 + eo) = cvt2(vv2);
    *(u32x2*)(Vl + 3 * 1088 + eo) = cvt2(vv3);
    *(u32x2*)(Ql + 0 * 1088 + eo) = cvt2(qv0);
    *(u32x2*)(Ql + 2 * 1088 + eo) = cvt2(qv1);
    // cond map: flat ushort idx G = tid*8 -> pos = 1 + (G>>10)*2,
    // e = (tid>>3)&15, d = (tid&7)*8 (already bf16, no convert)
    {
        const int cp = 1 + ((tid >> 7) << 1);
        const int co = cp * 1088 + ((tid >> 3) & 15) * 68 + (tid & 7) * 8;
        *(u32x2*)(Ql + co)     = (u32x2){cv[0], cv[1]};
        *(u32x2*)(Ql + co + 4) = (u32x2){cv[2], cv[3]};
    }
    __syncthreads();

    // ---------------- COMPUTE (verified v4 body, LDS-bf16 fragments) ------
    const ushort* Kw = Kl + wave * 1088;
    const ushort* Vw = Vl + wave * 1088;
    ushort*       Qw = Ql + wave * 1088;   // Q frags then O bounce

    union FU { short8 v; ushort u[8]; uint w[4]; u32x2 q[2]; };
    const int fo = l15 * 68 + quad * 8;
    FU ka, kb, qa, qb;
    ka.q[0] = *(const u32x2*)(Kw + fo);      ka.q[1] = *(const u32x2*)(Kw + fo + 4);
    kb.q[0] = *(const u32x2*)(Kw + fo + 32); kb.q[1] = *(const u32x2*)(Kw + fo + 36);
    qa.q[0] = *(const u32x2*)(Qw + fo);      qa.q[1] = *(const u32x2*)(Qw + fo + 4);
    qb.q[0] = *(const u32x2*)(Qw + fo + 32); qb.q[1] = *(const u32x2*)(Qw + fo + 36);

    // scores: S^T = K . CQ  (D: lane holds S[h=l15][e=quad*4+r])
    f32x4 sacc = (f32x4){0.f, 0.f, 0.f, 0.f};
    sacc = __builtin_amdgcn_mfma_f32_16x16x32_bf16(ka.v, qa.v, sacc, 0, 0, 0);
    sacc = __builtin_amdgcn_mfma_f32_16x16x32_bf16(kb.v, qb.v, sacc, 0, 0, 0);

    float s0 = (mv[0] == 0u) ? -1e20f : sacc[0] * 0.125f;
    float s1 = (mv[1] == 0u) ? -1e20f : sacc[1] * 0.125f;
    float s2 = (mv[2] == 0u) ? -1e20f : sacc[2] * 0.125f;
    float s3 = (mv[3] == 0u) ? -1e20f : sacc[3] * 0.125f;

    // softmax over e: in-lane (4 e's) then cross-quad shfl_xor
    float mx = fmaxf(fmaxf(s0, s1), fmaxf(s2, s3));
    mx = fmaxf(mx, __shfl_xor(mx, 16));
    mx = fmaxf(mx, __shfl_xor(mx, 32));
    const float e0 = __expf(s0 - mx), e1 = __expf(s1 - mx);
    const float e2 = __expf(s2 - mx), e3 = __expf(s3 - mx);
    float sum = e0 + e1 + e2 + e3;
    sum += __shfl_xor(sum, 16);
    sum += __shfl_xor(sum, 32);
    const float inv = 1.f / sum;                 // fully-masked row -> 1/16

    const uint pk01 = (uint)f2b(e0 * inv) | ((uint)f2b(e1 * inv) << 16);
    const uint pk23 = (uint)f2b(e2 * inv) | ((uint)f2b(e3 * inv) << 16);

    // transpose P into B-frag layout (4 shuffles, e>=16 zero-padded)
    const int srcA = (quad * 32 + l15) & 63;
    const int srcB = (quad * 32 + 16 + l15) & 63;
    FU pf;
    {
        const uint w0 = (uint)__shfl((int)pk01, srcA);
        const uint w1 = (uint)__shfl((int)pk23, srcA);
        const uint w2 = (uint)__shfl((int)pk01, srcB);
        const uint w3 = (uint)__shfl((int)pk23, srcB);
        const bool lo = (lane < 32);
        pf.w[0] = lo ? w0 : 0u; pf.w[1] = lo ? w1 : 0u;
        pf.w[2] = lo ? w2 : 0u; pf.w[3] = lo ? w3 : 0u;
    }

    // PV: per d-slice, A = V^T (bf16 straight from LDS), B = P.
    // D: lane holds O[h=l15][d0 + quad*4 + r] -> bounce into Qw (dead, wave-
    // private, LDS in-order per wave -> no barrier needed).
    const int eb = (quad & 1) * 8;
#pragma unroll
    for (int sl = 0; sl < 4; ++sl) {
        const int d0 = sl * 16;
        FU vf;
#pragma unroll
        for (int j = 0; j < 8; ++j)
            vf.u[j] = Vw[(eb + j) * 68 + d0 + l15];
        f32x4 oacc = (f32x4){0.f, 0.f, 0.f, 0.f};
        oacc = __builtin_amdgcn_mfma_f32_16x16x32_bf16(vf.v, pf.v, oacc, 0, 0, 0);
        u32x2 ow;
        ow[0] = (uint)f2b(oacc[0]) | ((uint)f2b(oacc[1]) << 16);
        ow[1] = (uint)f2b(oacc[2]) | ((uint)f2b(oacc[3]) << 16);
        *(u32x2*)(Qw + l15 * 68 + d0 + quad * 4) = ow;
    }

    // read back linearly (lane covers ushorts [lane*8, lane*8+8) and
    // [512+lane*8, ...)) and store as two contiguous 1KB instructions
    {
        const int h1 = lane >> 3, dd = (lane & 7) * 8;
        FU o1, o2;
        o1.q[0] = *(const u32x2*)(Qw + h1 * 68 + dd);
        o1.q[1] = *(const u32x2*)(Qw + h1 * 68 + dd + 4);
        o2.q[0] = *(const u32x2*)(Qw + (8 + h1) * 68 + dd);
        o2.q[1] = *(const u32x2*)(Qw + (8 + h1) * 68 + dd + 4);
        ushort* orow = attout + ((size_t)p << 10);
        *(short8*)(orow + lane * 8)       = o1.v;
        *(short8*)(orow + 512 + lane * 8) = o2.v;
    }
}

// ---------------------------------------------------------------------------
extern "C" void kernel_launch(void* const* d_in, const int* in_sizes, int n_in,
                              void* d_out, int out_size, void* d_ws, size_t ws_size,
                              hipStream_t stream)
{
    const float* values    = (const float*)d_in[0];
    const float* keys      = (const float*)d_in[1];
    const float* queries   = (const float*)d_in[2];
    const int*   mask      = (const int*)  d_in[3];
    const float* condition = (const float*)d_in[4];
    const float* Wc        = (const float*)d_in[5];
    const float* bc        = (const float*)d_in[6];
    const float* Wo        = (const float*)d_in[7];
    const float* bo        = (const float*)d_in[8];
    float* out = (float*)d_out;

    // workspace (48 MB total, with liveness-based aliasing):
    //  [0,16MB)  condfeat bf16 (8192x1024)      live: gemm1 -> attn
    //  [16,48MB) attout  bf16 (16384x1024)      live: attn -> gemm3
    //  cond_bf (8MB) + Wc_bf (1MB) alias attout (dead before attn writes it)
    //  Wo_bf (2MB) aliases condfeat (converted after attn, condfeat then dead)
    ushort* condfeat = (ushort*)d_ws;
    ushort* attout   = condfeat + (size_t)NB * SQ * EMB;
    ushort* cond_bf  = attout;
    ushort* Wc_bf    = attout + (size_t)NB * SQ * CDIM;
    ushort* Wo_bf    = condfeat;

    // converts needed before gemm1
    cvt_f32_bf16<<<(NB * SQ * CDIM / 4 + 255) / 256, 256, 0, stream>>>(
        condition, cond_bf, NB * SQ * CDIM / 4);
    cvt_f32_bf16<<<(EMB * CDIM / 4 + 255) / 256, 256, 0, stream>>>(
        Wc, Wc_bf, EMB * CDIM / 4);

    // 1) cond_feat = condition @ Wc^T + bc   (8192x1024, K=512) -> bf16
    {
        dim3 grid((NB * SQ) / 128, EMB / 128);
        gemm_bt_bias<ushort><<<grid, 256, 0, stream>>>(
            cond_bf, Wc_bf, bc, condfeat, NB * SQ, EMB, CDIM);
    }

    // 2) per-position 16x16 attention -> att_out (bf16), 4 positions/block
    attn_kernel<<<(NB * SKV) / POSB, 256, 0, stream>>>(queries, condfeat, keys,
                                                       values, mask, attout);

    // convert Wo after attn (aliases dead condfeat)
    cvt_f32_bf16<<<(EMB * EMB / 4 + 255) / 256, 256, 0, stream>>>(
        Wo, Wo_bf, EMB * EMB / 4);

    // 3) out = att_out @ Wo^T + bo   (16384x1024, K=1024) -> f32
    {
        dim3 grid((NB * SKV) / 128, EMB / 128);
        gemm_bt_bias<float><<<grid, 256, 0, stream>>>(
            attout, Wo_bf, bo, out, NB * SKV, EMB, EMB);
    }
}